// Round 1
// 871.610 us; speedup vs baseline: 1.2291x; 1.2291x over previous
//
#include <hip/hip_runtime.h>
#include <stdint.h>

typedef __attribute__((ext_vector_type(8))) short bf16x8;
typedef __attribute__((ext_vector_type(4))) float f32x4;

__device__ __forceinline__ unsigned short f2bf(float f) {
  union { float f; uint32_t u; } v; v.f = f;
  uint32_t r = (v.u + 0x7fffu + ((v.u >> 16) & 1u)) >> 16;
  return (unsigned short)r;
}

// async global->LDS, 16B per lane; LDS dest is wave-uniform base + lane*16 (HW adds it)
__device__ __forceinline__ void async16(const void* g, void* l) {
  __builtin_amdgcn_global_load_lds(
      (const __attribute__((address_space(1))) void*)(uintptr_t)g,
      (__attribute__((address_space(3))) void*)(uint32_t)(uintptr_t)l,
      16, 0, 0);
}

// ---------------- weight transpose fp32(K,N) -> bf16(N,K) ----------------
__global__ __launch_bounds__(256) void transpose_bf16(
    const float* __restrict__ in, unsigned short* __restrict__ out, int N, int K) {
  __shared__ float tile[32][33];
  int tx = threadIdx.x & 31, ty = threadIdx.x >> 5;  // 32 x 8
  int n0 = blockIdx.x * 32, k0 = blockIdx.y * 32;
#pragma unroll
  for (int i = 0; i < 32; i += 8)
    tile[ty + i][tx] = in[(size_t)(k0 + ty + i) * N + n0 + tx];
  __syncthreads();
#pragma unroll
  for (int i = 0; i < 32; i += 8)
    out[(size_t)(n0 + ty + i) * K + k0 + tx] = f2bf(tile[tx][ty + i]);
}

// ---------------- patch gather: maps (B,64,21,21) f32 -> patches (B*49,576) bf16 ----
__global__ __launch_bounds__(256) void gather_patches(
    const float* __restrict__ maps, unsigned short* __restrict__ P) {
  int bh = blockIdx.x;
  int b = bh / 7, h = bh % 7;
  __shared__ float lds[4032];  // [c][s1][y] = c*63 + s1*21 + y
  const float* mb = maps + (size_t)b * 64 * 441;
  for (int f = threadIdx.x; f < 4032; f += 256) {
    int c = f / 63, rem = f % 63;
    int s1 = rem / 21, y = rem % 21;
    lds[f] = mb[(size_t)c * 441 + (3 * h + s1) * 21 + y];
  }
  __syncthreads();
  unsigned short* pb = P + ((size_t)b * 49 + (size_t)h * 7) * 576;
#pragma unroll
  for (int w = 0; w < 7; ++w) {
    for (int ep = threadIdx.x; ep < 288; ep += 256) {
      int e = ep * 2;
      int c = e & 63, s2 = (e >> 6) % 3, s1 = e / 192;
      float v0 = lds[c * 63 + s1 * 21 + 3 * w + s2];
      float v1 = lds[(c + 1) * 63 + s1 * 21 + 3 * w + s2];
      ushort2 o; o.x = f2bf(v0); o.y = f2bf(v1);
      *(ushort2*)(pb + (size_t)w * 576 + e) = o;
    }
  }
}

// ---------------- tiny-K first layer: H = relu(X @ W1 + b1) -> bf16 -----------------
// 16 rows per block (W1 reuse), thread t -> cols 4t..4t+3
__global__ __launch_bounds__(256) void mlp1_small(
    const float* __restrict__ X, const float* __restrict__ W1,
    const float* __restrict__ b1, unsigned short* __restrict__ H, int K) {
  int t = threadIdx.x;
  size_t r0 = (size_t)blockIdx.x * 16;
  float4 bias = ((const float4*)b1)[t];
  float acc[16][4];
#pragma unroll
  for (int rr = 0; rr < 16; ++rr) {
    acc[rr][0] = bias.x; acc[rr][1] = bias.y; acc[rr][2] = bias.z; acc[rr][3] = bias.w;
  }
  for (int k = 0; k < K; ++k) {
    float4 w = ((const float4*)(W1 + (size_t)k * 1024))[t];
#pragma unroll
    for (int rr = 0; rr < 16; ++rr) {
      float x = X[(r0 + rr) * K + k];
      acc[rr][0] = fmaf(x, w.x, acc[rr][0]);
      acc[rr][1] = fmaf(x, w.y, acc[rr][1]);
      acc[rr][2] = fmaf(x, w.z, acc[rr][2]);
      acc[rr][3] = fmaf(x, w.w, acc[rr][3]);
    }
  }
#pragma unroll
  for (int rr = 0; rr < 16; ++rr) {
    ushort4 o;
    o.x = f2bf(fmaxf(acc[rr][0], 0.0f));
    o.y = f2bf(fmaxf(acc[rr][1], 0.0f));
    o.z = f2bf(fmaxf(acc[rr][2], 0.0f));
    o.w = f2bf(fmaxf(acc[rr][3], 0.0f));
    *(ushort4*)(H + (r0 + rr) * 1024 + 4 * t) = o;
  }
}

// ---------------- PE tables: pep (49,1024), pes (32,1024) f32 -----------------------
__global__ __launch_bounds__(256) void pe_kernel(
    const float* __restrict__ sy, float* __restrict__ pep, float* __restrict__ pes) {
  int r = blockIdx.x, i = threadIdx.x;
  float f = powf(1.0e-4f, (4.0f * (float)i) / 1024.0f);
  float x, y; float* dst;
  if (r < 49) {
    x = (float)(3 * (r / 7) + 1); y = (float)(3 * (r % 7) + 1);
    dst = pep + (size_t)r * 1024;
  } else {
    int s = r - 49;
    x = sy[s * 8 + 0]; y = sy[s * 8 + 1];
    dst = pes + (size_t)s * 1024;
  }
  float sx, cx, syv, cyv;
  sincosf(x * f, &sx, &cx);
  sincosf(y * f, &syv, &cyv);
  dst[2 * i] = sx; dst[2 * i + 1] = cx;
  dst[512 + 2 * i] = syv; dst[512 + 2 * i + 1] = cyv;
}

// ---------------- 256x256 MFMA GEMM, BK=32, triple-buffered counted-vmcnt pipeline --
// C = A(M,K) @ Bt(1024,K)^T + bias ; mode 0: relu->bf16 outb ; mode 1: +pe scatter outf
// 8 waves (2M x 4N), per-wave 128x64 output (acc[8][4] f32x4).
// LDS per buffer: A 256x32 bf16 (16KB, XOR-swizzled) + B 256x32 bf16 (16KB). 3 bufs = 96KB.
// Swizzle: byte = row*64 + 16*(k8 ^ ((row>>1)&3)); write side pre-swizzles the GLOBAL
// source address (global_load_lds writes linearly), read side applies the same XOR.
__global__ __launch_bounds__(512, 2) void gemm256(
    const unsigned short* __restrict__ A, const unsigned short* __restrict__ Bt,
    const float* __restrict__ bias, const float* __restrict__ pe,
    unsigned short* __restrict__ outb, float* __restrict__ outf,
    int M, int K, int mode, int rp, int col_base) {
  __shared__ __align__(16) char lds[3][32768];
  const int t = threadIdx.x;
  const int wave = t >> 6, lane = t & 63;
  const int l15 = lane & 15, quad = lane >> 4;
  const int wm = wave >> 2, wn = wave & 3;

  // bijective XCD-aware block swizzle (consecutive wg share the A panel)
  const int nbx = gridDim.x;
  const int nwg = nbx * gridDim.y;
  const int orig = blockIdx.y * nbx + blockIdx.x;
  const int q = nwg >> 3, r8 = nwg & 7;
  const int xcd = orig & 7, off = orig >> 3;
  const int wg = (xcd < r8 ? xcd * (q + 1) : r8 * (q + 1) + (xcd - r8) * q) + off;
  const int bn = wg % nbx, bm = wg / nbx;

  const size_t rA0 = (size_t)bm * 256;
  const size_t rB0 = (size_t)bn * 256;

  // staging: per instruction, 512 lanes x 16B = 8KB = 128 rows x 64B.
  // linear LDS addr L = chunk*8192 + wave*1024 + lane*16 -> row = L>>6, slot = (L>>4)&3.
  // k8 fetched = slot ^ ((row>>1)&3) = (t&3) ^ ((t>>3)&3).
  const int ke = (((t & 3) ^ ((t >> 3) & 3)) * 8);  // element offset of this lane's 8 bf16
  const unsigned short* pA = A + (rA0 + (t >> 2)) * (size_t)K + ke;
  const unsigned short* pB = Bt + (rB0 + (t >> 2)) * (size_t)K + ke;

  // read-side addressing (per-thread constants)
  const int aoff0 = (wm * 128 + l15) * 64;
  const int boff0 = (wn * 64 + l15) * 64;
  const int kx = ((quad ^ ((l15 >> 1) & 3)) << 4);  // swizzled 16B slot

  const int NT = K >> 5;  // K-tiles of 32
  f32x4 acc[8][4] = {};

  // ---- prologue: stage tiles 0 and 1, wait for tile 0 only (counted vmcnt) ----
  async16(pA, lds[0] + wave * 1024);
  async16(pA + (size_t)128 * K, lds[0] + 8192 + wave * 1024);
  async16(pB, lds[0] + 16384 + wave * 1024);
  async16(pB + (size_t)128 * K, lds[0] + 24576 + wave * 1024);
  if (NT > 1) {
    async16(pA + 32, lds[1] + wave * 1024);
    async16(pA + (size_t)128 * K + 32, lds[1] + 8192 + wave * 1024);
    async16(pB + 32, lds[1] + 16384 + wave * 1024);
    async16(pB + (size_t)128 * K + 32, lds[1] + 24576 + wave * 1024);
    asm volatile("s_waitcnt vmcnt(4)" ::: "memory");
  } else {
    asm volatile("s_waitcnt vmcnt(0)" ::: "memory");
  }
  __builtin_amdgcn_s_barrier();

  int bc = 0;
  for (int tt = 0; tt < NT; ++tt) {
    const char* La = lds[bc];
    const char* Lb = La + 16384;
    int bs = bc + 2; if (bs >= 3) bs -= 3;
    const bool pf = (tt + 2) < NT;
    const int kt = (tt + 2) << 5;  // element k-offset of tile being prefetched

    // ---- phase 0: A-low fragments + all B fragments; prefetch A of tile t+2
    bf16x8 av[4], bv[4];
#pragma unroll
    for (int i = 0; i < 4; ++i)
      av[i] = *(const bf16x8*)(La + aoff0 + i * 1024 + kx);
#pragma unroll
    for (int j = 0; j < 4; ++j)
      bv[j] = *(const bf16x8*)(Lb + boff0 + j * 1024 + kx);
    if (pf) {
      async16(pA + kt, lds[bs] + wave * 1024);
      async16(pA + (size_t)128 * K + kt, lds[bs] + 8192 + wave * 1024);
    }
    __builtin_amdgcn_s_barrier();
    __builtin_amdgcn_s_setprio(1);
#pragma unroll
    for (int i = 0; i < 4; ++i)
#pragma unroll
      for (int j = 0; j < 4; ++j)
        acc[i][j] = __builtin_amdgcn_mfma_f32_16x16x32_bf16(av[i], bv[j], acc[i][j], 0, 0, 0);
    __builtin_amdgcn_s_setprio(0);
    __builtin_amdgcn_s_barrier();

    // ---- phase 1: A-high fragments (B reused from regs); prefetch B of tile t+2
    bf16x8 aw[4];
#pragma unroll
    for (int i = 0; i < 4; ++i)
      aw[i] = *(const bf16x8*)(La + aoff0 + (4 + i) * 1024 + kx);
    if (pf) {
      async16(pB + kt, lds[bs] + 16384 + wave * 1024);
      async16(pB + (size_t)128 * K + kt, lds[bs] + 24576 + wave * 1024);
    }
    __builtin_amdgcn_s_barrier();
    __builtin_amdgcn_s_setprio(1);
#pragma unroll
    for (int i = 0; i < 4; ++i)
#pragma unroll
      for (int j = 0; j < 4; ++j)
        acc[4 + i][j] = __builtin_amdgcn_mfma_f32_16x16x32_bf16(aw[i], bv[j], acc[4 + i][j], 0, 0, 0);
    __builtin_amdgcn_s_setprio(0);
    // tile boundary: guarantee tile t+1 resident; newest 4 outstanding = tile t+2
    if (pf) asm volatile("s_waitcnt vmcnt(4)" ::: "memory");
    else    asm volatile("s_waitcnt vmcnt(0)" ::: "memory");
    __builtin_amdgcn_s_barrier();
    bc = bc + 1; if (bc >= 3) bc = 0;
  }

  // ---- epilogue ----
  const int gc0 = bn * 256 + wn * 64 + l15;
  float bs4[4];
#pragma unroll
  for (int j = 0; j < 4; ++j) bs4[j] = bias[gc0 + j * 16];

  if (mode == 0) {
#pragma unroll
    for (int i = 0; i < 8; ++i) {
      int gr0 = bm * 256 + wm * 128 + i * 16 + quad * 4;
#pragma unroll
      for (int r = 0; r < 4; ++r) {
        size_t row = (size_t)(gr0 + r);
#pragma unroll
        for (int j = 0; j < 4; ++j) {
          float v = acc[i][j][r] + bs4[j];
          outb[row * 1024 + gc0 + j * 16] = f2bf(fmaxf(v, 0.0f));
        }
      }
    }
  } else {
#pragma unroll
    for (int i = 0; i < 8; ++i) {
      int gr0 = bm * 256 + wm * 128 + i * 16 + quad * 4;
#pragma unroll
      for (int r = 0; r < 4; ++r) {
        int row = gr0 + r;
        int bb = row / rp;
        int p = row - bb * rp;
        size_t orow = (size_t)bb * 82 + (size_t)col_base + (size_t)p;
#pragma unroll
        for (int j = 0; j < 4; ++j) {
          float v = acc[i][j][r] + bs4[j];
          if (pe) v += pe[(size_t)p * 1024 + gc0 + j * 16];
          outf[orow * 1024 + gc0 + j * 16] = v;
        }
      }
    }
  }
}

extern "C" void kernel_launch(void* const* d_in, const int* in_sizes, int n_in,
                              void* d_out, int out_size, void* d_ws, size_t ws_size,
                              hipStream_t stream) {
  const float* maps = (const float*)d_in[0];
  const float* sy   = (const float*)d_in[1];
  const float* gs   = (const float*)d_in[2];
  const float* Wp1  = (const float*)d_in[3];
  const float* bp1  = (const float*)d_in[4];
  const float* Wp2  = (const float*)d_in[5];
  const float* bp2  = (const float*)d_in[6];
  const float* Ws1  = (const float*)d_in[7];
  const float* bs1  = (const float*)d_in[8];
  const float* Ws2  = (const float*)d_in[9];
  const float* bs2  = (const float*)d_in[10];
  const float* Wg1  = (const float*)d_in[11];
  const float* bg1  = (const float*)d_in[12];
  const float* Wg2  = (const float*)d_in[13];
  const float* bg2  = (const float*)d_in[14];
  float* out = (float*)d_out;

  const int B  = in_sizes[0] / (64 * 21 * 21);  // 1024
  const int Mp = B * 49;                        // 50176 (256 | Mp)
  const int Ms = B * 32;                        // 32768
  const int Mg = B;                             // 1024

  char* p = (char*)d_ws;
  auto alloc = [&](size_t bytes) { char* r = p; p += (bytes + 255) & ~(size_t)255; return r; };
  unsigned short* pat  = (unsigned short*)alloc((size_t)Mp * 576 * 2);
  unsigned short* hp   = (unsigned short*)alloc((size_t)Mp * 1024 * 2);
  unsigned short* hs   = (unsigned short*)alloc((size_t)Ms * 1024 * 2);
  unsigned short* hg   = (unsigned short*)alloc((size_t)Mg * 1024 * 2);
  unsigned short* wp1t = (unsigned short*)alloc((size_t)1024 * 576 * 2);
  unsigned short* wp2t = (unsigned short*)alloc((size_t)1024 * 1024 * 2);
  unsigned short* ws2t = (unsigned short*)alloc((size_t)1024 * 1024 * 2);
  unsigned short* wg2t = (unsigned short*)alloc((size_t)1024 * 1024 * 2);
  float* pep = (float*)alloc((size_t)49 * 1024 * 4);
  float* pes = (float*)alloc((size_t)32 * 1024 * 4);

  // weights -> transposed bf16 (Bt layout, N x K)
  transpose_bf16<<<dim3(1024 / 32, 576 / 32), 256, 0, stream>>>(Wp1, wp1t, 1024, 576);
  transpose_bf16<<<dim3(32, 32), 256, 0, stream>>>(Wp2, wp2t, 1024, 1024);
  transpose_bf16<<<dim3(32, 32), 256, 0, stream>>>(Ws2, ws2t, 1024, 1024);
  transpose_bf16<<<dim3(32, 32), 256, 0, stream>>>(Wg2, wg2t, 1024, 1024);

  // patch gather -> bf16
  gather_patches<<<B * 7, 256, 0, stream>>>(maps, pat);

  // tiny-K first layers
  mlp1_small<<<Ms / 16, 256, 0, stream>>>(sy, Ws1, bs1, hs, 8);
  mlp1_small<<<Mg / 16, 256, 0, stream>>>(gs, Wg1, bg1, hg, 16);

  // positional-encoding tables
  pe_kernel<<<81, 256, 0, stream>>>(sy, pep, pes);

  // big MFMA GEMMs (256x256 tiles, N=1024 -> gridDim.x = 4)
  gemm256<<<dim3(4, Mp / 256), 512, 0, stream>>>(pat, wp1t, bp1, nullptr, hp, nullptr, Mp, 576, 0, 0, 0);
  gemm256<<<dim3(4, Mp / 256), 512, 0, stream>>>(hp, wp2t, bp2, pep, nullptr, out, Mp, 1024, 1, 49, 33);
  gemm256<<<dim3(4, Ms / 256), 512, 0, stream>>>(hs, ws2t, bs2, pes, nullptr, out, Ms, 1024, 1, 32, 0);
  gemm256<<<dim3(4, Mg / 256), 512, 0, stream>>>(hg, wg2t, bg2, nullptr, nullptr, out, Mg, 1024, 1, 1, 32);

  (void)n_in; (void)out_size; (void)ws_size;
}

// Round 2
// 815.806 us; speedup vs baseline: 1.3132x; 1.0684x over previous
//
#include <hip/hip_runtime.h>
#include <stdint.h>

typedef __attribute__((ext_vector_type(8))) short bf16x8;
typedef __attribute__((ext_vector_type(4))) float f32x4;

__device__ __forceinline__ unsigned short f2bf(float f) {
  union { float f; uint32_t u; } v; v.f = f;
  uint32_t r = (v.u + 0x7fffu + ((v.u >> 16) & 1u)) >> 16;
  return (unsigned short)r;
}

// async global->LDS, 16B per lane; LDS dest is wave-uniform base + lane*16 (HW adds it)
__device__ __forceinline__ void async16(const void* g, void* l) {
  __builtin_amdgcn_global_load_lds(
      (const __attribute__((address_space(1))) void*)(uintptr_t)g,
      (__attribute__((address_space(3))) void*)(uint32_t)(uintptr_t)l,
      16, 0, 0);
}

// ================= prep (one dispatch): gather + mlp1 x2 + transpose x4 + pe =======
union PrepLds { float gbuf[4032]; float tile[32][33]; };

__device__ __forceinline__ void gather_body(PrepLds& u, const float* __restrict__ maps,
                                            unsigned short* __restrict__ pat, int b) {
  int b0 = b / 7, h = b % 7;
  const float* mb = maps + (size_t)b0 * 64 * 441;
  for (int f = threadIdx.x; f < 4032; f += 256) {
    int c = f / 63, rem = f % 63;
    int s1 = rem / 21, y = rem % 21;
    u.gbuf[f] = mb[(size_t)c * 441 + (3 * h + s1) * 21 + y];
  }
  __syncthreads();
  unsigned short* pb = pat + ((size_t)b0 * 49 + (size_t)h * 7) * 576;
  // 7 w-positions x 144 ushort4 groups = 1008 work items
  for (int idx = threadIdx.x; idx < 1008; idx += 256) {
    int w = idx / 144, ep = idx - w * 144;
    int e = ep * 4;  // elements e..e+3 share s1,s2 (c = e&63 in {0,4,...,60})
    int c = e & 63, s2 = (e >> 6) % 3, s1 = e / 192;
    int base = c * 63 + s1 * 21 + 3 * w + s2;
    ushort4 o;
    o.x = f2bf(u.gbuf[base]);
    o.y = f2bf(u.gbuf[base + 63]);
    o.z = f2bf(u.gbuf[base + 126]);
    o.w = f2bf(u.gbuf[base + 189]);
    *(ushort4*)(pb + (size_t)w * 576 + e) = o;
  }
}

__device__ __forceinline__ void mlp1_body(const float* __restrict__ X,
                                          const float* __restrict__ W1,
                                          const float* __restrict__ b1,
                                          unsigned short* __restrict__ H,
                                          int K, size_t r0) {
  int t = threadIdx.x;
  float4 bias = ((const float4*)b1)[t];
  float acc[16][4];
#pragma unroll
  for (int rr = 0; rr < 16; ++rr) {
    acc[rr][0] = bias.x; acc[rr][1] = bias.y; acc[rr][2] = bias.z; acc[rr][3] = bias.w;
  }
  for (int k = 0; k < K; ++k) {
    float4 w = ((const float4*)(W1 + (size_t)k * 1024))[t];
#pragma unroll
    for (int rr = 0; rr < 16; ++rr) {
      float x = X[(r0 + rr) * K + k];
      acc[rr][0] = fmaf(x, w.x, acc[rr][0]);
      acc[rr][1] = fmaf(x, w.y, acc[rr][1]);
      acc[rr][2] = fmaf(x, w.z, acc[rr][2]);
      acc[rr][3] = fmaf(x, w.w, acc[rr][3]);
    }
  }
#pragma unroll
  for (int rr = 0; rr < 16; ++rr) {
    ushort4 o;
    o.x = f2bf(fmaxf(acc[rr][0], 0.0f));
    o.y = f2bf(fmaxf(acc[rr][1], 0.0f));
    o.z = f2bf(fmaxf(acc[rr][2], 0.0f));
    o.w = f2bf(fmaxf(acc[rr][3], 0.0f));
    *(ushort4*)(H + (r0 + rr) * 1024 + 4 * t) = o;
  }
}

__device__ __forceinline__ void transpose_body(PrepLds& u, const float* __restrict__ in,
                                               unsigned short* __restrict__ out,
                                               int N, int K, int n0, int k0) {
  int tx = threadIdx.x & 31, ty = threadIdx.x >> 5;  // 32 x 8
#pragma unroll
  for (int i = 0; i < 32; i += 8)
    u.tile[ty + i][tx] = in[(size_t)(k0 + ty + i) * N + n0 + tx];
  __syncthreads();
#pragma unroll
  for (int i = 0; i < 32; i += 8)
    out[(size_t)(n0 + ty + i) * K + k0 + tx] = f2bf(u.tile[tx][ty + i]);
}

__device__ __forceinline__ void pe_body(const float* __restrict__ sy,
                                        float* __restrict__ pep, float* __restrict__ pes,
                                        int r) {
  int i = threadIdx.x;
  float f = powf(1.0e-4f, (4.0f * (float)i) / 1024.0f);
  float x, y; float* dst;
  if (r < 49) {
    x = (float)(3 * (r / 7) + 1); y = (float)(3 * (r % 7) + 1);
    dst = pep + (size_t)r * 1024;
  } else {
    int s = r - 49;
    x = sy[s * 8 + 0]; y = sy[s * 8 + 1];
    dst = pes + (size_t)s * 1024;
  }
  float sx, cx, syv, cyv;
  sincosf(x * f, &sx, &cx);
  sincosf(y * f, &syv, &cyv);
  dst[2 * i] = sx; dst[2 * i + 1] = cx;
  dst[512 + 2 * i] = syv; dst[512 + 2 * i + 1] = cyv;
}

__global__ __launch_bounds__(256) void prep_kernel(
    const float* maps, unsigned short* pat,
    const float* sy, const float* Ws1, const float* bs1, unsigned short* hs,
    const float* gs, const float* Wg1, const float* bg1, unsigned short* hg,
    const float* Wp1, unsigned short* wp1t, const float* Wp2, unsigned short* wp2t,
    const float* Ws2, unsigned short* ws2t, const float* Wg2, unsigned short* wg2t,
    float* pep, float* pes, int B) {
  __shared__ PrepLds u;
  int b = blockIdx.x, n;
  n = B * 7;
  if (b < n) { gather_body(u, maps, pat, b); return; }
  b -= n;
  n = B * 2;  // Ms/16 blocks for hs
  if (b < n) { mlp1_body(sy, Ws1, bs1, hs, 8, (size_t)b * 16); return; }
  b -= n;
  n = B / 16;  // Mg/16 blocks for hg
  if (b < n) { mlp1_body(gs, Wg1, bg1, hg, 16, (size_t)b * 16); return; }
  b -= n;
  if (b < 576) { transpose_body(u, Wp1, wp1t, 1024, 576, (b & 31) * 32, (b >> 5) * 32); return; }
  b -= 576;
  if (b < 1024) { transpose_body(u, Wp2, wp2t, 1024, 1024, (b & 31) * 32, (b >> 5) * 32); return; }
  b -= 1024;
  if (b < 1024) { transpose_body(u, Ws2, ws2t, 1024, 1024, (b & 31) * 32, (b >> 5) * 32); return; }
  b -= 1024;
  if (b < 1024) { transpose_body(u, Wg2, wg2t, 1024, 1024, (b & 31) * 32, (b >> 5) * 32); return; }
  b -= 1024;
  pe_body(sy, pep, pes, b);
}

// ================= 256x256 MFMA GEMM body (triple-buffer, counted vmcnt) ===========
// Identical schedule to the verified round-1 kernel; mode is now a template param.
// N fixed at 1024 -> 4 bn tiles; idx = bm*4 + bn.
template <int MODE>
__device__ __forceinline__ void gemm_body(char* lds0, int idx,
    const unsigned short* __restrict__ A, const unsigned short* __restrict__ Bt,
    const float* __restrict__ bias, const float* __restrict__ pe,
    unsigned short* __restrict__ outb, float* __restrict__ outf,
    int K, int rp, int col_base) {
  const int t = threadIdx.x;
  const int wave = t >> 6, lane = t & 63;
  const int l15 = lane & 15, quad = lane >> 4;
  const int wm = wave >> 2, wn = wave & 3;
  const int bn = idx & 3, bm = idx >> 2;
  const size_t rA0 = (size_t)bm * 256;
  const size_t rB0 = (size_t)bn * 256;

  const int ke = (((t & 3) ^ ((t >> 3) & 3)) * 8);  // pre-swizzled global k-offset
  const unsigned short* pA = A + (rA0 + (t >> 2)) * (size_t)K + ke;
  const unsigned short* pB = Bt + (rB0 + (t >> 2)) * (size_t)K + ke;

  const int aoff0 = (wm * 128 + l15) * 64;
  const int boff0 = (wn * 64 + l15) * 64;
  const int kx = ((quad ^ ((l15 >> 1) & 3)) << 4);  // swizzled 16B slot on read

  const int NT = K >> 5;
  f32x4 acc[8][4] = {};

  // prologue: stage tiles 0 and 1, wait for tile 0 only
  async16(pA, lds0 + wave * 1024);
  async16(pA + (size_t)128 * K, lds0 + 8192 + wave * 1024);
  async16(pB, lds0 + 16384 + wave * 1024);
  async16(pB + (size_t)128 * K, lds0 + 24576 + wave * 1024);
  if (NT > 1) {
    async16(pA + 32, lds0 + 32768 + wave * 1024);
    async16(pA + (size_t)128 * K + 32, lds0 + 32768 + 8192 + wave * 1024);
    async16(pB + 32, lds0 + 32768 + 16384 + wave * 1024);
    async16(pB + (size_t)128 * K + 32, lds0 + 32768 + 24576 + wave * 1024);
    asm volatile("s_waitcnt vmcnt(4)" ::: "memory");
  } else {
    asm volatile("s_waitcnt vmcnt(0)" ::: "memory");
  }
  __builtin_amdgcn_s_barrier();

  int bc = 0;
  for (int tt = 0; tt < NT; ++tt) {
    const char* La = lds0 + bc * 32768;
    const char* Lb = La + 16384;
    int bs = bc + 2; if (bs >= 3) bs -= 3;
    char* Ls = lds0 + bs * 32768;
    const bool pf = (tt + 2) < NT;
    const int kt = (tt + 2) << 5;

    // phase 0: A-low + B fragments; prefetch A of tile t+2
    bf16x8 av[4], bv[4];
#pragma unroll
    for (int i = 0; i < 4; ++i)
      av[i] = *(const bf16x8*)(La + aoff0 + i * 1024 + kx);
#pragma unroll
    for (int j = 0; j < 4; ++j)
      bv[j] = *(const bf16x8*)(Lb + boff0 + j * 1024 + kx);
    if (pf) {
      async16(pA + kt, Ls + wave * 1024);
      async16(pA + (size_t)128 * K + kt, Ls + 8192 + wave * 1024);
    }
    __builtin_amdgcn_s_barrier();
    __builtin_amdgcn_s_setprio(1);
#pragma unroll
    for (int i = 0; i < 4; ++i)
#pragma unroll
      for (int j = 0; j < 4; ++j)
        acc[i][j] = __builtin_amdgcn_mfma_f32_16x16x32_bf16(av[i], bv[j], acc[i][j], 0, 0, 0);
    __builtin_amdgcn_s_setprio(0);
    __builtin_amdgcn_s_barrier();

    // phase 1: A-high fragments (B reused); prefetch B of tile t+2
    bf16x8 aw[4];
#pragma unroll
    for (int i = 0; i < 4; ++i)
      aw[i] = *(const bf16x8*)(La + aoff0 + (4 + i) * 1024 + kx);
    if (pf) {
      async16(pB + kt, Ls + 16384 + wave * 1024);
      async16(pB + (size_t)128 * K + kt, Ls + 24576 + wave * 1024);
    }
    __builtin_amdgcn_s_barrier();
    __builtin_amdgcn_s_setprio(1);
#pragma unroll
    for (int i = 0; i < 4; ++i)
#pragma unroll
      for (int j = 0; j < 4; ++j)
        acc[4 + i][j] = __builtin_amdgcn_mfma_f32_16x16x32_bf16(aw[i], bv[j], acc[4 + i][j], 0, 0, 0);
    __builtin_amdgcn_s_setprio(0);
    if (pf) asm volatile("s_waitcnt vmcnt(4)" ::: "memory");
    else    asm volatile("s_waitcnt vmcnt(0)" ::: "memory");
    __builtin_amdgcn_s_barrier();
    bc = bc + 1; if (bc >= 3) bc = 0;
  }

  // epilogue
  const int gc0 = bn * 256 + wn * 64 + l15;
  float bs4[4];
#pragma unroll
  for (int j = 0; j < 4; ++j) bs4[j] = bias[gc0 + j * 16];

  if (MODE == 0) {
#pragma unroll
    for (int i = 0; i < 8; ++i) {
      int gr0 = bm * 256 + wm * 128 + i * 16 + quad * 4;
#pragma unroll
      for (int r = 0; r < 4; ++r) {
        size_t row = (size_t)(gr0 + r);
#pragma unroll
        for (int j = 0; j < 4; ++j) {
          float v = acc[i][j][r] + bs4[j];
          outb[row * 1024 + gc0 + j * 16] = f2bf(fmaxf(v, 0.0f));
        }
      }
    }
  } else {
#pragma unroll
    for (int i = 0; i < 8; ++i) {
      int gr0 = bm * 256 + wm * 128 + i * 16 + quad * 4;
#pragma unroll
      for (int r = 0; r < 4; ++r) {
        int row = gr0 + r;
        int bb = row / rp;
        int p = row - bb * rp;
        size_t orow = (size_t)bb * 82 + (size_t)col_base + (size_t)p;
#pragma unroll
        for (int j = 0; j < 4; ++j) {
          float v = acc[i][j][r] + bs4[j];
          if (pe) v += pe[(size_t)p * 1024 + gc0 + j * 16];
          outf[orow * 1024 + gc0 + j * 16] = v;
        }
      }
    }
  }
}

__device__ __forceinline__ int xcd_swizzle(int orig, int nwg) {
  int q = nwg >> 3, r8 = nwg & 7;
  int xcd = orig & 7, off = orig >> 3;
  return (xcd < r8 ? xcd * (q + 1) : r8 * (q + 1) + (xcd - r8) * q) + off;
}

// layer-1 patch GEMM (mode 0, relu -> bf16)
__global__ __launch_bounds__(512, 2) void gemm_l1(
    const unsigned short* __restrict__ A, const unsigned short* __restrict__ Bt,
    const float* __restrict__ bias, unsigned short* __restrict__ outb,
    int K, int nwg) {
  __shared__ __align__(16) char lds[3][32768];
  int wg = xcd_swizzle(blockIdx.x, nwg);
  gemm_body<0>(&lds[0][0], wg, A, Bt, bias, nullptr, outb, nullptr, K, 0, 0);
}

// grouped layer-2 GEMMs (mode 1, +pe scatter into out)
struct G3 {
  const unsigned short* A[3];
  const unsigned short* Bt[3];
  const float* bias[3];
  const float* pe[3];
  int K[3], rp[3], cb[3], bstart[3];
};

__global__ __launch_bounds__(512, 2) void gemm_l2(G3 g, float* __restrict__ out, int nwg) {
  __shared__ __align__(16) char lds[3][32768];
  int wg = xcd_swizzle(blockIdx.x, nwg);
  int grp = (wg >= g.bstart[2]) ? 2 : (wg >= g.bstart[1] ? 1 : 0);
  int idx = wg - g.bstart[grp];
  gemm_body<1>(&lds[0][0], idx, g.A[grp], g.Bt[grp], g.bias[grp], g.pe[grp],
               nullptr, out, g.K[grp], g.rp[grp], g.cb[grp]);
}

extern "C" void kernel_launch(void* const* d_in, const int* in_sizes, int n_in,
                              void* d_out, int out_size, void* d_ws, size_t ws_size,
                              hipStream_t stream) {
  const float* maps = (const float*)d_in[0];
  const float* sy   = (const float*)d_in[1];
  const float* gs   = (const float*)d_in[2];
  const float* Wp1  = (const float*)d_in[3];
  const float* bp1  = (const float*)d_in[4];
  const float* Wp2  = (const float*)d_in[5];
  const float* bp2  = (const float*)d_in[6];
  const float* Ws1  = (const float*)d_in[7];
  const float* bs1  = (const float*)d_in[8];
  const float* Ws2  = (const float*)d_in[9];
  const float* bs2  = (const float*)d_in[10];
  const float* Wg1  = (const float*)d_in[11];
  const float* bg1  = (const float*)d_in[12];
  const float* Wg2  = (const float*)d_in[13];
  const float* bg2  = (const float*)d_in[14];
  float* out = (float*)d_out;

  const int B  = in_sizes[0] / (64 * 21 * 21);  // 1024
  const int Mp = B * 49;                        // 50176
  const int Ms = B * 32;                        // 32768
  const int Mg = B;                             // 1024

  char* p = (char*)d_ws;
  auto alloc = [&](size_t bytes) { char* r = p; p += (bytes + 255) & ~(size_t)255; return r; };
  unsigned short* pat  = (unsigned short*)alloc((size_t)Mp * 576 * 2);
  unsigned short* hp   = (unsigned short*)alloc((size_t)Mp * 1024 * 2);
  unsigned short* hs   = (unsigned short*)alloc((size_t)Ms * 1024 * 2);
  unsigned short* hg   = (unsigned short*)alloc((size_t)Mg * 1024 * 2);
  unsigned short* wp1t = (unsigned short*)alloc((size_t)1024 * 576 * 2);
  unsigned short* wp2t = (unsigned short*)alloc((size_t)1024 * 1024 * 2);
  unsigned short* ws2t = (unsigned short*)alloc((size_t)1024 * 1024 * 2);
  unsigned short* wg2t = (unsigned short*)alloc((size_t)1024 * 1024 * 2);
  float* pep = (float*)alloc((size_t)49 * 1024 * 4);
  float* pes = (float*)alloc((size_t)32 * 1024 * 4);

  // dispatch 1: all prep, concurrent
  int prep_blocks = B * 7 + B * 2 + B / 16 + 576 + 3 * 1024 + 81;
  prep_kernel<<<prep_blocks, 256, 0, stream>>>(
      maps, pat, sy, Ws1, bs1, hs, gs, Wg1, bg1, hg,
      Wp1, wp1t, Wp2, wp2t, Ws2, ws2t, Wg2, wg2t, pep, pes, B);

  // dispatch 2: layer-1 patch GEMM (needs pat, wp1t)
  int nwg1 = (Mp / 256) * 4;  // 784
  gemm_l1<<<nwg1, 512, 0, stream>>>(pat, wp1t, bp1, hp, 576, nwg1);

  // dispatch 3: grouped layer-2 GEMMs (needs hp, hs, hg, transposed weights, pe tables)
  G3 g;
  g.A[0] = hp;   g.Bt[0] = wp2t; g.bias[0] = bp2; g.pe[0] = pep;
  g.K[0] = 1024; g.rp[0] = 49;   g.cb[0] = 33;
  g.A[1] = hs;   g.Bt[1] = ws2t; g.bias[1] = bs2; g.pe[1] = pes;
  g.K[1] = 1024; g.rp[1] = 32;   g.cb[1] = 0;
  g.A[2] = hg;   g.Bt[2] = wg2t; g.bias[2] = bg2; g.pe[2] = nullptr;
  g.K[2] = 1024; g.rp[2] = 1;    g.cb[2] = 32;
  int n2 = (Mp / 256) * 4;            // 784
  int n3 = n2 + (Ms / 256) * 4;       // 1296
  int nwg2 = n3 + (Mg / 256) * 4;     // 1312
  g.bstart[0] = 0; g.bstart[1] = n2; g.bstart[2] = n3;
  gemm_l2<<<nwg2, 512, 0, stream>>>(g, out, nwg2);

  (void)n_in; (void)out_size; (void)ws_size;
}

// Round 3
// 804.499 us; speedup vs baseline: 1.3316x; 1.0141x over previous
//
#include <hip/hip_runtime.h>
#include <stdint.h>

typedef __attribute__((ext_vector_type(8))) short bf16x8;
typedef __attribute__((ext_vector_type(4))) float f32x4;

__device__ __forceinline__ unsigned short f2bf(float f) {
  union { float f; uint32_t u; } v; v.f = f;
  uint32_t r = (v.u + 0x7fffu + ((v.u >> 16) & 1u)) >> 16;
  return (unsigned short)r;
}

// async global->LDS, 16B per lane; LDS dest is wave-uniform base + lane*16 (HW adds it)
__device__ __forceinline__ void async16(const void* g, void* l) {
  __builtin_amdgcn_global_load_lds(
      (const __attribute__((address_space(1))) void*)(uintptr_t)g,
      (__attribute__((address_space(3))) void*)(uint32_t)(uintptr_t)l,
      16, 0, 0);
}

// ================= prep (one dispatch): gather + mlp1 x2 + transpose x4 + pe =======
union PrepLds { float gbuf[4032]; float tile[32][33]; };

__device__ __forceinline__ void gather_body(PrepLds& u, const float* __restrict__ maps,
                                            unsigned short* __restrict__ pat, int b) {
  int b0 = b / 7, h = b % 7;
  const float* mb = maps + (size_t)b0 * 64 * 441;
  for (int f = threadIdx.x; f < 4032; f += 256) {
    int c = f / 63, rem = f % 63;
    int s1 = rem / 21, y = rem % 21;
    u.gbuf[f] = mb[(size_t)c * 441 + (3 * h + s1) * 21 + y];
  }
  __syncthreads();
  unsigned short* pb = pat + ((size_t)b0 * 49 + (size_t)h * 7) * 576;
  // 7 w-positions x 144 ushort4 groups = 1008 work items
  for (int idx = threadIdx.x; idx < 1008; idx += 256) {
    int w = idx / 144, ep = idx - w * 144;
    int e = ep * 4;  // elements e..e+3 share s1,s2 (c = e&63 in {0,4,...,60})
    int c = e & 63, s2 = (e >> 6) % 3, s1 = e / 192;
    int base = c * 63 + s1 * 21 + 3 * w + s2;
    ushort4 o;
    o.x = f2bf(u.gbuf[base]);
    o.y = f2bf(u.gbuf[base + 63]);
    o.z = f2bf(u.gbuf[base + 126]);
    o.w = f2bf(u.gbuf[base + 189]);
    *(ushort4*)(pb + (size_t)w * 576 + e) = o;
  }
}

__device__ __forceinline__ void mlp1_body(const float* __restrict__ X,
                                          const float* __restrict__ W1,
                                          const float* __restrict__ b1,
                                          unsigned short* __restrict__ H,
                                          int K, size_t r0) {
  int t = threadIdx.x;
  float4 bias = ((const float4*)b1)[t];
  float acc[16][4];
#pragma unroll
  for (int rr = 0; rr < 16; ++rr) {
    acc[rr][0] = bias.x; acc[rr][1] = bias.y; acc[rr][2] = bias.z; acc[rr][3] = bias.w;
  }
  for (int k = 0; k < K; ++k) {
    float4 w = ((const float4*)(W1 + (size_t)k * 1024))[t];
#pragma unroll
    for (int rr = 0; rr < 16; ++rr) {
      float x = X[(r0 + rr) * K + k];
      acc[rr][0] = fmaf(x, w.x, acc[rr][0]);
      acc[rr][1] = fmaf(x, w.y, acc[rr][1]);
      acc[rr][2] = fmaf(x, w.z, acc[rr][2]);
      acc[rr][3] = fmaf(x, w.w, acc[rr][3]);
    }
  }
#pragma unroll
  for (int rr = 0; rr < 16; ++rr) {
    ushort4 o;
    o.x = f2bf(fmaxf(acc[rr][0], 0.0f));
    o.y = f2bf(fmaxf(acc[rr][1], 0.0f));
    o.z = f2bf(fmaxf(acc[rr][2], 0.0f));
    o.w = f2bf(fmaxf(acc[rr][3], 0.0f));
    *(ushort4*)(H + (r0 + rr) * 1024 + 4 * t) = o;
  }
}

__device__ __forceinline__ void transpose_body(PrepLds& u, const float* __restrict__ in,
                                               unsigned short* __restrict__ out,
                                               int N, int K, int n0, int k0) {
  int tx = threadIdx.x & 31, ty = threadIdx.x >> 5;  // 32 x 8
#pragma unroll
  for (int i = 0; i < 32; i += 8)
    u.tile[ty + i][tx] = in[(size_t)(k0 + ty + i) * N + n0 + tx];
  __syncthreads();
#pragma unroll
  for (int i = 0; i < 32; i += 8)
    out[(size_t)(n0 + ty + i) * K + k0 + tx] = f2bf(u.tile[tx][ty + i]);
}

__device__ __forceinline__ void pe_body(const float* __restrict__ sy,
                                        float* __restrict__ pep, float* __restrict__ pes,
                                        int r) {
  int i = threadIdx.x;
  float f = powf(1.0e-4f, (4.0f * (float)i) / 1024.0f);
  float x, y; float* dst;
  if (r < 49) {
    x = (float)(3 * (r / 7) + 1); y = (float)(3 * (r % 7) + 1);
    dst = pep + (size_t)r * 1024;
  } else {
    int s = r - 49;
    x = sy[s * 8 + 0]; y = sy[s * 8 + 1];
    dst = pes + (size_t)s * 1024;
  }
  float sx, cx, syv, cyv;
  sincosf(x * f, &sx, &cx);
  sincosf(y * f, &syv, &cyv);
  dst[2 * i] = sx; dst[2 * i + 1] = cx;
  dst[512 + 2 * i] = syv; dst[512 + 2 * i + 1] = cyv;
}

__global__ __launch_bounds__(256) void prep_kernel(
    const float* maps, unsigned short* pat,
    const float* sy, const float* Ws1, const float* bs1, unsigned short* hs,
    const float* gs, const float* Wg1, const float* bg1, unsigned short* hg,
    const float* Wp1, unsigned short* wp1t, const float* Wp2, unsigned short* wp2t,
    const float* Ws2, unsigned short* ws2t, const float* Wg2, unsigned short* wg2t,
    float* pep, float* pes, int B) {
  __shared__ PrepLds u;
  int b = blockIdx.x, n;
  n = B * 7;
  if (b < n) { gather_body(u, maps, pat, b); return; }
  b -= n;
  n = B * 2;  // Ms/16 blocks for hs
  if (b < n) { mlp1_body(sy, Ws1, bs1, hs, 8, (size_t)b * 16); return; }
  b -= n;
  n = B / 16;  // Mg/16 blocks for hg
  if (b < n) { mlp1_body(gs, Wg1, bg1, hg, 16, (size_t)b * 16); return; }
  b -= n;
  if (b < 576) { transpose_body(u, Wp1, wp1t, 1024, 576, (b & 31) * 32, (b >> 5) * 32); return; }
  b -= 576;
  if (b < 1024) { transpose_body(u, Wp2, wp2t, 1024, 1024, (b & 31) * 32, (b >> 5) * 32); return; }
  b -= 1024;
  if (b < 1024) { transpose_body(u, Ws2, ws2t, 1024, 1024, (b & 31) * 32, (b >> 5) * 32); return; }
  b -= 1024;
  if (b < 1024) { transpose_body(u, Wg2, wg2t, 1024, 1024, (b & 31) * 32, (b >> 5) * 32); return; }
  b -= 1024;
  pe_body(sy, pep, pes, b);
}

// ================= 256x256 MFMA GEMM body (triple-buffer, counted vmcnt) ===========
// One barrier per K-tile (the only one required: tile t writes buf (t+2)%3 ==
// (t-1)%3, whose readers finished before the end-of-tile-(t-1) barrier).
// ds_reads + prefetches issued up front, one setprio MFMA cluster — compiler emits
// counted lgkmcnt, waves skew within the tile so LDS and MFMA pipes overlap.
template <int MODE>
__device__ __forceinline__ void gemm_body(char* lds0, int idx,
    const unsigned short* __restrict__ A, const unsigned short* __restrict__ Bt,
    const float* __restrict__ bias, const float* __restrict__ pe,
    unsigned short* __restrict__ outb, float* __restrict__ outf,
    int K, int rp, int col_base) {
  const int t = threadIdx.x;
  const int wave = t >> 6, lane = t & 63;
  const int l15 = lane & 15, quad = lane >> 4;
  const int wm = wave >> 2, wn = wave & 3;
  const int bn = idx & 3, bm = idx >> 2;
  const size_t rA0 = (size_t)bm * 256;
  const size_t rB0 = (size_t)bn * 256;

  const int ke = (((t & 3) ^ ((t >> 3) & 3)) * 8);  // pre-swizzled global k-offset
  const unsigned short* pA = A + (rA0 + (t >> 2)) * (size_t)K + ke;
  const unsigned short* pB = Bt + (rB0 + (t >> 2)) * (size_t)K + ke;

  const int aoff0 = (wm * 128 + l15) * 64;
  const int boff0 = (wn * 64 + l15) * 64;
  const int kx = ((quad ^ ((l15 >> 1) & 3)) << 4);  // swizzled 16B slot on read

  const int NT = K >> 5;
  f32x4 acc[8][4] = {};

  // prologue: stage tiles 0 and 1, wait for tile 0 only
  async16(pA, lds0 + wave * 1024);
  async16(pA + (size_t)128 * K, lds0 + 8192 + wave * 1024);
  async16(pB, lds0 + 16384 + wave * 1024);
  async16(pB + (size_t)128 * K, lds0 + 24576 + wave * 1024);
  if (NT > 1) {
    async16(pA + 32, lds0 + 32768 + wave * 1024);
    async16(pA + (size_t)128 * K + 32, lds0 + 32768 + 8192 + wave * 1024);
    async16(pB + 32, lds0 + 32768 + 16384 + wave * 1024);
    async16(pB + (size_t)128 * K + 32, lds0 + 32768 + 24576 + wave * 1024);
    asm volatile("s_waitcnt vmcnt(4)" ::: "memory");
  } else {
    asm volatile("s_waitcnt vmcnt(0)" ::: "memory");
  }
  __builtin_amdgcn_s_barrier();

  int bc = 0;
  for (int tt = 0; tt < NT; ++tt) {
    const char* La = lds0 + bc * 32768;
    const char* Lb = La + 16384;
    int bs = bc + 2; if (bs >= 3) bs -= 3;
    char* Ls = lds0 + bs * 32768;
    const bool pf = (tt + 2) < NT;
    const int kt = (tt + 2) << 5;

    // all fragment reads + prefetches for this tile, then one MFMA cluster
    bf16x8 av[4], bv[4], aw[4];
#pragma unroll
    for (int i = 0; i < 4; ++i)
      av[i] = *(const bf16x8*)(La + aoff0 + i * 1024 + kx);
#pragma unroll
    for (int j = 0; j < 4; ++j)
      bv[j] = *(const bf16x8*)(Lb + boff0 + j * 1024 + kx);
    if (pf) {
      async16(pA + kt, Ls + wave * 1024);
      async16(pA + (size_t)128 * K + kt, Ls + 8192 + wave * 1024);
    }
#pragma unroll
    for (int i = 0; i < 4; ++i)
      aw[i] = *(const bf16x8*)(La + aoff0 + (4 + i) * 1024 + kx);
    if (pf) {
      async16(pB + kt, Ls + 16384 + wave * 1024);
      async16(pB + (size_t)128 * K + kt, Ls + 24576 + wave * 1024);
    }
    __builtin_amdgcn_s_setprio(1);
#pragma unroll
    for (int i = 0; i < 4; ++i)
#pragma unroll
      for (int j = 0; j < 4; ++j)
        acc[i][j] = __builtin_amdgcn_mfma_f32_16x16x32_bf16(av[i], bv[j], acc[i][j], 0, 0, 0);
#pragma unroll
    for (int i = 0; i < 4; ++i)
#pragma unroll
      for (int j = 0; j < 4; ++j)
        acc[4 + i][j] = __builtin_amdgcn_mfma_f32_16x16x32_bf16(aw[i], bv[j], acc[4 + i][j], 0, 0, 0);
    __builtin_amdgcn_s_setprio(0);
    if (pf) asm volatile("s_waitcnt vmcnt(4)" ::: "memory");
    else    asm volatile("s_waitcnt vmcnt(0)" ::: "memory");
    __builtin_amdgcn_s_barrier();
    bc = bc + 1; if (bc >= 3) bc = 0;
  }

  // epilogue
  const int gc0 = bn * 256 + wn * 64 + l15;
  float bs4[4];
#pragma unroll
  for (int j = 0; j < 4; ++j) bs4[j] = bias[gc0 + j * 16];

  if (MODE == 0) {
#pragma unroll
    for (int i = 0; i < 8; ++i) {
      int gr0 = bm * 256 + wm * 128 + i * 16 + quad * 4;
#pragma unroll
      for (int r = 0; r < 4; ++r) {
        size_t row = (size_t)(gr0 + r);
#pragma unroll
        for (int j = 0; j < 4; ++j) {
          float v = acc[i][j][r] + bs4[j];
          outb[row * 1024 + gc0 + j * 16] = f2bf(fmaxf(v, 0.0f));
        }
      }
    }
  } else {
#pragma unroll
    for (int i = 0; i < 8; ++i) {
      int gr0 = bm * 256 + wm * 128 + i * 16 + quad * 4;
#pragma unroll
      for (int r = 0; r < 4; ++r) {
        int row = gr0 + r;
        int bb = row / rp;
        int p = row - bb * rp;
        size_t orow = (size_t)bb * 82 + (size_t)col_base + (size_t)p;
#pragma unroll
        for (int j = 0; j < 4; ++j) {
          float v = acc[i][j][r] + bs4[j];
          if (pe) v += pe[(size_t)p * 1024 + gc0 + j * 16];
          outf[orow * 1024 + gc0 + j * 16] = v;
        }
      }
    }
  }
}

__device__ __forceinline__ int xcd_swizzle(int orig, int nwg) {
  int q = nwg >> 3, r8 = nwg & 7;
  int xcd = orig & 7, off = orig >> 3;
  return (xcd < r8 ? xcd * (q + 1) : r8 * (q + 1) + (xcd - r8) * q) + off;
}

// layer-1 patch GEMM (mode 0, relu -> bf16)
__global__ __launch_bounds__(512, 2) void gemm_l1(
    const unsigned short* __restrict__ A, const unsigned short* __restrict__ Bt,
    const float* __restrict__ bias, unsigned short* __restrict__ outb,
    int K, int nwg) {
  __shared__ __align__(16) char lds[3][32768];
  int wg = xcd_swizzle(blockIdx.x, nwg);
  gemm_body<0>(&lds[0][0], wg, A, Bt, bias, nullptr, outb, nullptr, K, 0, 0);
}

// grouped layer-2 GEMMs (mode 1, +pe scatter into out)
struct G3 {
  const unsigned short* A[3];
  const unsigned short* Bt[3];
  const float* bias[3];
  const float* pe[3];
  int K[3], rp[3], cb[3], bstart[3];
};

__global__ __launch_bounds__(512, 2) void gemm_l2(G3 g, float* __restrict__ out, int nwg) {
  __shared__ __align__(16) char lds[3][32768];
  int wg = xcd_swizzle(blockIdx.x, nwg);
  int grp = (wg >= g.bstart[2]) ? 2 : (wg >= g.bstart[1] ? 1 : 0);
  int idx = wg - g.bstart[grp];
  gemm_body<1>(&lds[0][0], idx, g.A[grp], g.Bt[grp], g.bias[grp], g.pe[grp],
               nullptr, out, g.K[grp], g.rp[grp], g.cb[grp]);
}

extern "C" void kernel_launch(void* const* d_in, const int* in_sizes, int n_in,
                              void* d_out, int out_size, void* d_ws, size_t ws_size,
                              hipStream_t stream) {
  const float* maps = (const float*)d_in[0];
  const float* sy   = (const float*)d_in[1];
  const float* gs   = (const float*)d_in[2];
  const float* Wp1  = (const float*)d_in[3];
  const float* bp1  = (const float*)d_in[4];
  const float* Wp2  = (const float*)d_in[5];
  const float* bp2  = (const float*)d_in[6];
  const float* Ws1  = (const float*)d_in[7];
  const float* bs1  = (const float*)d_in[8];
  const float* Ws2  = (const float*)d_in[9];
  const float* bs2  = (const float*)d_in[10];
  const float* Wg1  = (const float*)d_in[11];
  const float* bg1  = (const float*)d_in[12];
  const float* Wg2  = (const float*)d_in[13];
  const float* bg2  = (const float*)d_in[14];
  float* out = (float*)d_out;

  const int B  = in_sizes[0] / (64 * 21 * 21);  // 1024
  const int Mp = B * 49;                        // 50176
  const int Ms = B * 32;                        // 32768
  const int Mg = B;                             // 1024

  char* p = (char*)d_ws;
  auto alloc = [&](size_t bytes) { char* r = p; p += (bytes + 255) & ~(size_t)255; return r; };
  unsigned short* pat  = (unsigned short*)alloc((size_t)Mp * 576 * 2);
  unsigned short* hp   = (unsigned short*)alloc((size_t)Mp * 1024 * 2);
  unsigned short* hs   = (unsigned short*)alloc((size_t)Ms * 1024 * 2);
  unsigned short* hg   = (unsigned short*)alloc((size_t)Mg * 1024 * 2);
  unsigned short* wp1t = (unsigned short*)alloc((size_t)1024 * 576 * 2);
  unsigned short* wp2t = (unsigned short*)alloc((size_t)1024 * 1024 * 2);
  unsigned short* ws2t = (unsigned short*)alloc((size_t)1024 * 1024 * 2);
  unsigned short* wg2t = (unsigned short*)alloc((size_t)1024 * 1024 * 2);
  float* pep = (float*)alloc((size_t)49 * 1024 * 4);
  float* pes = (float*)alloc((size_t)32 * 1024 * 4);

  // dispatch 1: all prep, concurrent
  int prep_blocks = B * 7 + B * 2 + B / 16 + 576 + 3 * 1024 + 81;
  prep_kernel<<<prep_blocks, 256, 0, stream>>>(
      maps, pat, sy, Ws1, bs1, hs, gs, Wg1, bg1, hg,
      Wp1, wp1t, Wp2, wp2t, Ws2, ws2t, Wg2, wg2t, pep, pes, B);

  // dispatch 2: layer-1 patch GEMM (needs pat, wp1t)
  int nwg1 = (Mp / 256) * 4;  // 784
  gemm_l1<<<nwg1, 512, 0, stream>>>(pat, wp1t, bp1, hp, 576, nwg1);

  // dispatch 3: grouped layer-2 GEMMs (needs hp, hs, hg, transposed weights, pe tables)
  G3 g;
  g.A[0] = hp;   g.Bt[0] = wp2t; g.bias[0] = bp2; g.pe[0] = pep;
  g.K[0] = 1024; g.rp[0] = 49;   g.cb[0] = 33;
  g.A[1] = hs;   g.Bt[1] = ws2t; g.bias[1] = bs2; g.pe[1] = pes;
  g.K[1] = 1024; g.rp[1] = 32;   g.cb[1] = 0;
  g.A[2] = hg;   g.Bt[2] = wg2t; g.bias[2] = bg2; g.pe[2] = nullptr;
  g.K[2] = 1024; g.rp[2] = 1;    g.cb[2] = 32;
  int n2 = (Mp / 256) * 4;            // 784
  int n3 = n2 + (Ms / 256) * 4;       // 1296
  int nwg2 = n3 + (Mg / 256) * 4;     // 1312
  g.bstart[0] = 0; g.bstart[1] = n2; g.bstart[2] = n3;
  gemm_l2<<<nwg2, 512, 0, stream>>>(g, out, nwg2);

  (void)n_in; (void)out_size; (void)ws_size;
}